// Round 6
// baseline (169.520 us; speedup 1.0000x reference)
//
#include <hip/hip_runtime.h>

#define BB 32
#define HH 256
#define WW 256
#define HW (HH*WW)
#define HW4 (HW/4)
#define KP1 9
#define KNEG 8
#define MARGIN_F 10.0f
#define RATIO_INV_F 10000.0f

// grid roles (order: scattered/heavy first, lightest last)
#define NGATH 4
#define NCO   1024                  // corner-offset: 32 blocks/b, 2048 px
#define NCE0  512                   // out0 CE + t_corner scan + pos corrections: 16 blocks/b, 4096 px
#define NCE1  512                   // out1 CE dense: 16 blocks/b, 4096 px
#define GATH_BASE 0
#define CO_BASE   (NGATH)                 // 4
#define CE0_BASE  (NGATH + NCO)           // 1028
#define CE1_BASE  (NGATH + NCO + NCE0)    // 1540
#define GRID      (NGATH + NCO + NCE0 + NCE1)  // 2052

// per-block slot: 8 floats (32B). ws usage = 2052*32 B ≈ 66 KB. No zero-init
// needed: every slot we read is unconditionally written by its block.
// GATH slot: [l0, l1]
// CO   slot: [s0, s1]
// CE0  slot: [ce0(+corr0), s_pos, corr1, bo0, bo1]
// CE1  slot: [ce1]

__device__ __forceinline__ float fast_tanh(float x) {
    float xc = fminf(fmaxf(x, -15.f), 15.f);
    float t = __expf(2.f * xc);
    return (t - 1.f) / (t + 1.f);
}
__device__ __forceinline__ float fast_sigmoid(float x) {
    return 1.f / (1.f + __expf(-x));
}
__device__ __forceinline__ float smooth_l1(float d) {
    float ad = fabsf(d);
    return ad < 1.f ? 0.5f * d * d : ad - 0.5f;
}
__device__ __forceinline__ float el(const float4& v, int j) {
    return reinterpret_cast<const float*>(&v)[j];
}
__device__ __forceinline__ float nlse0(float c0, float c1) {
    const float mx = fmaxf(c0, c1);
    return mx + __logf(1.f + __expf(-fabsf(c0 - c1))) - c0;
}
// returns block-wide sum to ALL threads
__device__ __forceinline__ float block_sum(float x, float* scratch) {
    const int lane = threadIdx.x & 63;
    const int wid  = threadIdx.x >> 6;
#pragma unroll
    for (int off = 32; off; off >>= 1) x += __shfl_down(x, off);
    __syncthreads();
    if (lane == 0) scratch[wid] = x;
    __syncthreads();
    return scratch[0] + scratch[1] + scratch[2] + scratch[3];
}

__global__ __launch_bounds__(256) void ml_partial_kernel(
    const float* __restrict__ out0, const float* __restrict__ out1,
    const float* __restrict__ t_corner, const float* __restrict__ t_co,
    const float* __restrict__ t_bin,
    const int* __restrict__ anchors, const int* __restrict__ positives,
    const int* __restrict__ neg_zero, const int* __restrict__ neg_other,
    float* __restrict__ ws)
{
    __shared__ float scratch[4];
    const int bid = blockIdx.x;
    const int t = threadIdx.x;
    float* slot = ws + (size_t)bid * 8;

    if (bid < NGATH) {
        // ---------------- triplet gathers (l_center numerator) -------------
        const int gid = bid * 256 + t;
        float local0 = 0.f, local1 = 0.f;
        if (gid < 2 * BB * KP1) {
            const int s = gid / (BB * KP1);
            const int r = gid % (BB * KP1);
            const int b = r / KP1, c = r % KP1;
            const float* o = (s ? out1 : out0) + (size_t)b * 7 * HW;
            const int ia  = anchors  [b * KP1 + c];
            const int ip  = positives[b * KP1 + c];
            const int in1 = neg_zero [b * KP1 + c];
            const float va = o[ia], vp = o[ip], vn1 = o[in1];
            const float Dap = (va - vp) * (va - vp);
            const float h1 = fmaxf(0.f, Dap - (va - vn1) * (va - vn1) + MARGIN_F);
            float pc;
            if (c > 0) {
                const int in2 = neg_other[b * KNEG + (c - 1)];
                const float vn2 = o[in2];
                const float h2 = fmaxf(0.f, Dap - (va - vn2) * (va - vn2) + MARGIN_F);
                pc = 0.5f * (h1 + h2);
            } else {
                pc = h1;
            }
            if (s == 0) local0 = pc; else local1 = pc;
        }
        const float r0 = block_sum(local0, scratch);
        const float r1 = block_sum(local1, scratch);
        if (t == 0) { slot[0] = r0; slot[1] = r1; }

    } else if (bid < CE0_BASE) {
        // ---------------- corner-offset loss (both stacks) -----------------
        const int r = bid - CO_BASE;
        const int b = r >> 5;
        const int base = (r & 31) * 512;     // 2048 px per block
        const int p0 = base + t, p1 = base + 256 + t;
        const float4* tco4 = (const float4*)(t_co + (size_t)b * 2 * HW);
        const float4* o04  = (const float4*)(out0 + (size_t)b * 7 * HW);
        const float4* o14  = (const float4*)(out1 + (size_t)b * 7 * HW);
        const float4 tg0a = tco4[p0],           tg0b = tco4[p1];
        const float4 tg1a = tco4[HW4 + p0],     tg1b = tco4[HW4 + p1];
        const float4 a03a = o04[3 * HW4 + p0],  a03b = o04[3 * HW4 + p1];
        const float4 a04a = o04[4 * HW4 + p0],  a04b = o04[4 * HW4 + p1];
        const float4 a13a = o14[3 * HW4 + p0],  a13b = o14[3 * HW4 + p1];
        const float4 a14a = o14[4 * HW4 + p0],  a14b = o14[4 * HW4 + p1];
        float s0 = 0.f, s1 = 0.f;
#pragma unroll
        for (int j = 0; j < 4; ++j) {
            float tgt0 = el(tg0a, j), tgt1 = el(tg1a, j);
            float m0 = (tgt0 != 0.f) ? RATIO_INV_F : 1.f;
            float m1 = (tgt1 != 0.f) ? RATIO_INV_F : 1.f;
            s0 += m0 * smooth_l1(fast_tanh(el(a03a, j)) * (float)HH - tgt0)
                + m1 * smooth_l1(fast_tanh(el(a04a, j)) * (float)WW - tgt1);
            s1 += m0 * smooth_l1(fast_tanh(el(a13a, j)) * (float)HH - tgt0)
                + m1 * smooth_l1(fast_tanh(el(a14a, j)) * (float)WW - tgt1);
            tgt0 = el(tg0b, j); tgt1 = el(tg1b, j);
            m0 = (tgt0 != 0.f) ? RATIO_INV_F : 1.f;
            m1 = (tgt1 != 0.f) ? RATIO_INV_F : 1.f;
            s0 += m0 * smooth_l1(fast_tanh(el(a03b, j)) * (float)HH - tgt0)
                + m1 * smooth_l1(fast_tanh(el(a04b, j)) * (float)WW - tgt1);
            s1 += m0 * smooth_l1(fast_tanh(el(a13b, j)) * (float)HH - tgt0)
                + m1 * smooth_l1(fast_tanh(el(a14b, j)) * (float)WW - tgt1);
        }
        const float r0 = block_sum(s0, scratch);
        const float r1 = block_sum(s1, scratch);
        if (t == 0) { slot[0] = r0; slot[1] = r1; }

    } else if (bid < CE1_BASE) {
        // ------ out0 corner-CE dense + t_corner scan + pos corrections -----
        const int r = bid - CE0_BASE;
        const int b = r >> 4;
        const int base = (r & 15) * 1024;    // 4096 px per block
        const float* oa = out0 + (size_t)b * 7 * HW;
        const float* ob = out1 + (size_t)b * 7 * HW;
        const float4* tc4 = (const float4*)(t_corner + (size_t)b * HW);
        const float4* c1p = (const float4*)(oa + HW);
        const float4* c2p = (const float4*)(oa + 2 * HW);
        float4 tcv[4], v1[4], v2[4];
#pragma unroll
        for (int k = 0; k < 4; ++k) tcv[k] = tc4[base + k * 256 + t];
#pragma unroll
        for (int k = 0; k < 4; ++k) v1[k] = c1p[base + k * 256 + t];
#pragma unroll
        for (int k = 0; k < 4; ++k) v2[k] = c2p[base + k * 256 + t];

        float ce0 = 0.f, s_pos = 0.f, corr1 = 0.f, bo0 = 0.f, bo1 = 0.f;
#pragma unroll
        for (int k = 0; k < 4; ++k) {
#pragma unroll
            for (int j = 0; j < 4; ++j) {
                const float a_c0 = el(v1[k], j), a_c1 = el(v2[k], j);
                ce0 += nlse0(a_c0, a_c1);
                const float pv = el(tcv[k], j);
                if (pv != 0.f) {
                    s_pos += pv;
                    const int p = 4 * (base + k * 256 + t) + j;
                    // scattered batch: stack1 c0/c1, ch5/6 both stacks, t_bin
                    const float tb0  = t_bin[(size_t)b * 2 * HW + p];
                    const float tb1  = t_bin[(size_t)b * 2 * HW + HW + p];
                    const float b_c0 = ob[HW + p],     b_c1 = ob[2 * HW + p];
                    const float a_o5 = oa[5 * HW + p], a_o6 = oa[6 * HW + p];
                    const float b_o5 = ob[5 * HW + p], b_o6 = ob[6 * HW + p];
                    // stack0 CE correction (values already in registers)
                    {
                        const float mx = fmaxf(a_c0, a_c1);
                        const float lse = mx + __logf(1.f + __expf(-fabsf(a_c0 - a_c1)));
                        ce0 += pv * ((lse - a_c1) * RATIO_INV_F - (lse - a_c0));
                        const float sb0 = fabsf(fast_sigmoid(a_o5) - 0.5f - tb0);
                        const float sb1 = fabsf(fast_sigmoid(a_o6) - 0.5f - tb1);
                        bo0 += (sb0 + sb1) * pv;
                    }
                    // stack1 corrections
                    {
                        const float mx = fmaxf(b_c0, b_c1);
                        const float lse = mx + __logf(1.f + __expf(-fabsf(b_c0 - b_c1)));
                        corr1 += pv * ((lse - b_c1) * RATIO_INV_F - (lse - b_c0));
                        const float sb0 = fabsf(fast_sigmoid(b_o5) - 0.5f - tb0);
                        const float sb1 = fabsf(fast_sigmoid(b_o6) - 0.5f - tb1);
                        bo1 += (sb0 + sb1) * pv;
                    }
                }
            }
        }
        const float r0 = block_sum(ce0,   scratch);
        const float r1 = block_sum(s_pos, scratch);
        const float r2 = block_sum(corr1, scratch);
        const float r3 = block_sum(bo0,   scratch);
        const float r4 = block_sum(bo1,   scratch);
        if (t == 0) { slot[0]=r0; slot[1]=r1; slot[2]=r2; slot[3]=r3; slot[4]=r4; }

    } else {
        // ---------------- out1 corner-CE dense ----------------------------
        const int r = bid - CE1_BASE;
        const int b = r >> 4;
        const int base = (r & 15) * 1024;    // 4096 px per block
        const float* o = out1 + (size_t)b * 7 * HW;
        const float4* c1p = (const float4*)(o + HW);
        const float4* c2p = (const float4*)(o + 2 * HW);
        float4 v1[4], v2[4];
#pragma unroll
        for (int k = 0; k < 4; ++k) v1[k] = c1p[base + k * 256 + t];
#pragma unroll
        for (int k = 0; k < 4; ++k) v2[k] = c2p[base + k * 256 + t];
        float sum = 0.f;
#pragma unroll
        for (int k = 0; k < 4; ++k)
#pragma unroll
            for (int j = 0; j < 4; ++j)
                sum += nlse0(el(v1[k], j), el(v2[k], j));
        const float r0 = block_sum(sum, scratch);
        if (t == 0) slot[0] = r0;
    }
}

// Finisher: sums per-block slots. One block.
__global__ __launch_bounds__(256) void ml_finish_kernel(
    const float* __restrict__ ws, float* __restrict__ out)
{
    const int i = threadIdx.x;
    if (i >= 2 * 97) return;
    const int s = i / 97, j = i % 97;
    const float invHW = 1.f / (float)HW;
    float val;
    if (j == 0) {
        float acc = 0.f;
        for (int g = 0; g < NGATH; ++g) acc += ws[(size_t)(GATH_BASE + g) * 8 + s];
        val = acc / (float)(KP1 * BB);
    } else if (j < 33) {
        const int b = j - 1;
        float acc = 0.f;
        if (s == 0) {
            for (int k = 0; k < 16; ++k)
                acc += ws[(size_t)(CE0_BASE + b * 16 + k) * 8 + 0];
        } else {
            for (int k = 0; k < 16; ++k)
                acc += ws[(size_t)(CE1_BASE + b * 16 + k) * 8 + 0]
                     + ws[(size_t)(CE0_BASE + b * 16 + k) * 8 + 2];
        }
        val = acc * invHW;
    } else if (j < 65) {
        const int b = j - 33;
        float acc = 0.f;
        for (int k = 0; k < 32; ++k)
            acc += ws[(size_t)(CO_BASE + b * 32 + k) * 8 + s];
        val = 0.25f * acc * invHW;
    } else {
        const int b = j - 65;
        float sp = 0.f, num = 0.f;
        for (int k = 0; k < 16; ++k) {
            const float* sl = ws + (size_t)(CE0_BASE + b * 16 + k) * 8;
            sp  += sl[1];
            num += sl[3 + s];
        }
        val = (sp > 0.f) ? (num / sp) : (num * invHW);
    }
    out[i] = val;
}

extern "C" void kernel_launch(void* const* d_in, const int* in_sizes, int n_in,
                              void* d_out, int out_size, void* d_ws, size_t ws_size,
                              hipStream_t stream) {
    const float* out0      = (const float*)d_in[0];
    const float* out1      = (const float*)d_in[1];
    const float* t_corner  = (const float*)d_in[2];
    const float* t_co      = (const float*)d_in[3];
    const float* t_bin     = (const float*)d_in[4];
    const int*   anchors   = (const int*)d_in[5];
    const int*   positives = (const int*)d_in[6];
    const int*   neg_zero  = (const int*)d_in[7];
    const int*   neg_other = (const int*)d_in[8];
    float* ws  = (float*)d_ws;
    float* out = (float*)d_out;

    ml_partial_kernel<<<GRID, 256, 0, stream>>>(out0, out1, t_corner, t_co, t_bin,
                                                anchors, positives, neg_zero,
                                                neg_other, ws);
    ml_finish_kernel<<<1, 256, 0, stream>>>(ws, out);
}

// Round 9
// 165.785 us; speedup vs baseline: 1.0225x; 1.0225x over previous
//
#include <hip/hip_runtime.h>

#define BB 32
#define HH 256
#define WW 256
#define HW (HH*WW)
#define HW4 (HW/4)
#define KP1 9
#define KNEG 8
#define MARGIN_F 10.0f
#define RATIO_INV_F 10000.0f

// grid roles: GATH (scattered, first) -> S0 (5 streams + corrections) -> S1 (4 streams)
#define NGATH 4
#define NS0   1024                 // out0 ch1-4 + t_corner scan: 32 blocks/b, 2048 px
#define NS1   1024                 // out1 ch1-4 dense:           32 blocks/b, 2048 px
#define GATH_BASE 0
#define S0_BASE   (NGATH)          // 4
#define S1_BASE   (NGATH + NS0)    // 1028
#define GRID      (NGATH + NS0 + NS1)  // 2052

// per-block slot: 8 floats (32B), plain stores (no zero-init needed).
// GATH: [l0, l1]
// S0  : [ce0, co0, s_pos, ce1corr, co1corr, bo0, bo1]
// S1  : [ce1, co1]

__device__ __forceinline__ float fast_tanh(float x) {
    float xc = fminf(fmaxf(x, -15.f), 15.f);
    float t = __expf(2.f * xc);
    return (t - 1.f) / (t + 1.f);
}
__device__ __forceinline__ float fast_sigmoid(float x) {
    return 1.f / (1.f + __expf(-x));
}
__device__ __forceinline__ float smooth_l1(float d) {
    float ad = fabsf(d);
    return ad < 1.f ? 0.5f * d * d : ad - 0.5f;
}
__device__ __forceinline__ float el(const float4& v, int j) {
    return reinterpret_cast<const float*>(&v)[j];
}
__device__ __forceinline__ float nlse0(float c0, float c1) {
    const float mx = fmaxf(c0, c1);
    return mx + __logf(1.f + __expf(-fabsf(c0 - c1))) - c0;
}
// block-wide sum broadcast to all threads
__device__ __forceinline__ float block_sum(float x, float* scratch) {
    const int lane = threadIdx.x & 63;
    const int wid  = threadIdx.x >> 6;
#pragma unroll
    for (int off = 32; off; off >>= 1) x += __shfl_down(x, off);
    __syncthreads();
    if (lane == 0) scratch[wid] = x;
    __syncthreads();
    return scratch[0] + scratch[1] + scratch[2] + scratch[3];
}

__global__ __launch_bounds__(256) void ml_partial_kernel(
    const float* __restrict__ out0, const float* __restrict__ out1,
    const float* __restrict__ t_corner, const float* __restrict__ t_co,
    const float* __restrict__ t_bin,
    const int* __restrict__ anchors, const int* __restrict__ positives,
    const int* __restrict__ neg_zero, const int* __restrict__ neg_other,
    float* __restrict__ ws)
{
    __shared__ float scratch[4];
    const int bid = blockIdx.x;
    const int t = threadIdx.x;
    float* slot = ws + (size_t)bid * 8;

    if (bid < NGATH) {
        // ---------------- triplet gathers (l_center numerator) -------------
        const int gid = bid * 256 + t;
        float local0 = 0.f, local1 = 0.f;
        if (gid < 2 * BB * KP1) {
            const int s = gid / (BB * KP1);
            const int r = gid % (BB * KP1);
            const int b = r / KP1, c = r % KP1;
            const float* o = (s ? out1 : out0) + (size_t)b * 7 * HW;
            const int ia  = anchors  [b * KP1 + c];
            const int ip  = positives[b * KP1 + c];
            const int in1 = neg_zero [b * KP1 + c];
            const float va = o[ia], vp = o[ip], vn1 = o[in1];
            const float Dap = (va - vp) * (va - vp);
            const float h1 = fmaxf(0.f, Dap - (va - vn1) * (va - vn1) + MARGIN_F);
            float pc;
            if (c > 0) {
                const int in2 = neg_other[b * KNEG + (c - 1)];
                const float vn2 = o[in2];
                const float h2 = fmaxf(0.f, Dap - (va - vn2) * (va - vn2) + MARGIN_F);
                pc = 0.5f * (h1 + h2);
            } else {
                pc = h1;
            }
            if (s == 0) local0 = pc; else local1 = pc;
        }
        const float r0 = block_sum(local0, scratch);
        const float r1 = block_sum(local1, scratch);
        if (t == 0) { slot[0] = r0; slot[1] = r1; }

    } else if (bid < S1_BASE) {
        // ------ out0: CE + CO dense + t_corner scan + ALL pos corrections --
        const int r = bid - S0_BASE;
        const int b = r >> 5;
        const int base4 = (r & 31) * 512;    // 2048 px per block (512 f4)
        const int p0 = base4 + t, p1 = base4 + 256 + t;
        const float* oa = out0 + (size_t)b * 7 * HW;
        const float* ob = out1 + (size_t)b * 7 * HW;
        const float4* tc4 = (const float4*)(t_corner + (size_t)b * HW);
        const float4* c1p = (const float4*)(oa + HW);
        const float4* c2p = (const float4*)(oa + 2 * HW);
        const float4* c3p = (const float4*)(oa + 3 * HW);
        const float4* c4p = (const float4*)(oa + 4 * HW);
        // 10 independent loads up front
        const float4 tca = tc4[p0], tcb = tc4[p1];
        const float4 v1a = c1p[p0], v1b = c1p[p1];
        const float4 v2a = c2p[p0], v2b = c2p[p1];
        const float4 v3a = c3p[p0], v3b = c3p[p1];
        const float4 v4a = c4p[p0], v4b = c4p[p1];

        float ce0 = 0.f, co0 = 0.f, s_pos = 0.f;
        float ce1c = 0.f, co1c = 0.f, bo0 = 0.f, bo1 = 0.f;
#pragma unroll
        for (int h = 0; h < 2; ++h) {
            const float4& tcv = h ? tcb : tca;
            const float4& v1 = h ? v1b : v1a;
            const float4& v2 = h ? v2b : v2a;
            const float4& v3 = h ? v3b : v3a;
            const float4& v4 = h ? v4b : v4a;
            const int pbase = 4 * (h ? p1 : p0);
#pragma unroll
            for (int j = 0; j < 4; ++j) {
                const float a_c1 = el(v1, j), a_c2 = el(v2, j);
                ce0 += nlse0(a_c1, a_c2);
                const float a_t3 = fast_tanh(el(v3, j)) * (float)HH;
                const float a_t4 = fast_tanh(el(v4, j)) * (float)WW;
                co0 += smooth_l1(a_t3) + smooth_l1(a_t4);
                const float pv = el(tcv, j);
                if (pv != 0.f) {
                    s_pos += pv;
                    const int p = pbase + j;
                    // scattered batch (12 loads, independent)
                    const float tgt0 = t_co[(size_t)b * 2 * HW + p];
                    const float tgt1 = t_co[(size_t)b * 2 * HW + HW + p];
                    const float tb0  = t_bin[(size_t)b * 2 * HW + p];
                    const float tb1  = t_bin[(size_t)b * 2 * HW + HW + p];
                    const float b_c1 = ob[HW + p],     b_c2 = ob[2 * HW + p];
                    const float b_o3 = ob[3 * HW + p], b_o4 = ob[4 * HW + p];
                    const float a_o5 = oa[5 * HW + p], a_o6 = oa[6 * HW + p];
                    const float b_o5 = ob[5 * HW + p], b_o6 = ob[6 * HW + p];
                    // CO corrections: m*sl1(co-tgt) - sl1(co); ==0 when tgt==0
                    const float m0 = (tgt0 != 0.f) ? RATIO_INV_F : 1.f;
                    const float m1 = (tgt1 != 0.f) ? RATIO_INV_F : 1.f;
                    co0 += m0 * smooth_l1(a_t3 - tgt0) - smooth_l1(a_t3)
                         + m1 * smooth_l1(a_t4 - tgt1) - smooth_l1(a_t4);
                    const float b_t3 = fast_tanh(b_o3) * (float)HH;
                    const float b_t4 = fast_tanh(b_o4) * (float)WW;
                    co1c += m0 * smooth_l1(b_t3 - tgt0) - smooth_l1(b_t3)
                          + m1 * smooth_l1(b_t4 - tgt1) - smooth_l1(b_t4);
                    // CE pos corrections
                    {
                        const float mx = fmaxf(a_c1, a_c2);
                        const float lse = mx + __logf(1.f + __expf(-fabsf(a_c1 - a_c2)));
                        ce0 += pv * ((lse - a_c2) * RATIO_INV_F - (lse - a_c1));
                    }
                    {
                        const float mx = fmaxf(b_c1, b_c2);
                        const float lse = mx + __logf(1.f + __expf(-fabsf(b_c1 - b_c2)));
                        ce1c += pv * ((lse - b_c2) * RATIO_INV_F - (lse - b_c1));
                    }
                    // bin-offset
                    bo0 += (fabsf(fast_sigmoid(a_o5) - 0.5f - tb0)
                          + fabsf(fast_sigmoid(a_o6) - 0.5f - tb1)) * pv;
                    bo1 += (fabsf(fast_sigmoid(b_o5) - 0.5f - tb0)
                          + fabsf(fast_sigmoid(b_o6) - 0.5f - tb1)) * pv;
                }
            }
        }
        const float r0 = block_sum(ce0,  scratch);
        const float r1 = block_sum(co0,  scratch);
        const float r2 = block_sum(s_pos,scratch);
        const float r3 = block_sum(ce1c, scratch);
        const float r4 = block_sum(co1c, scratch);
        const float r5 = block_sum(bo0,  scratch);
        const float r6 = block_sum(bo1,  scratch);
        if (t == 0) {
            slot[0]=r0; slot[1]=r1; slot[2]=r2; slot[3]=r3;
            slot[4]=r4; slot[5]=r5; slot[6]=r6;
        }

    } else {
        // ---------------- out1: CE + CO dense ------------------------------
        const int r = bid - S1_BASE;
        const int b = r >> 5;
        const int base4 = (r & 31) * 512;
        const int p0 = base4 + t, p1 = base4 + 256 + t;
        const float* o = out1 + (size_t)b * 7 * HW;
        const float4* c1p = (const float4*)(o + HW);
        const float4* c2p = (const float4*)(o + 2 * HW);
        const float4* c3p = (const float4*)(o + 3 * HW);
        const float4* c4p = (const float4*)(o + 4 * HW);
        const float4 v1a = c1p[p0], v1b = c1p[p1];
        const float4 v2a = c2p[p0], v2b = c2p[p1];
        const float4 v3a = c3p[p0], v3b = c3p[p1];
        const float4 v4a = c4p[p0], v4b = c4p[p1];
        float ce1 = 0.f, co1 = 0.f;
#pragma unroll
        for (int h = 0; h < 2; ++h) {
            const float4& v1 = h ? v1b : v1a;
            const float4& v2 = h ? v2b : v2a;
            const float4& v3 = h ? v3b : v3a;
            const float4& v4 = h ? v4b : v4a;
#pragma unroll
            for (int j = 0; j < 4; ++j) {
                ce1 += nlse0(el(v1, j), el(v2, j));
                co1 += smooth_l1(fast_tanh(el(v3, j)) * (float)HH)
                     + smooth_l1(fast_tanh(el(v4, j)) * (float)WW);
            }
        }
        const float r0 = block_sum(ce1, scratch);
        const float r1 = block_sum(co1, scratch);
        if (t == 0) { slot[0] = r0; slot[1] = r1; }
    }
}

// Finisher: sums per-block slots. One block.
__global__ __launch_bounds__(256) void ml_finish_kernel(
    const float* __restrict__ ws, float* __restrict__ out)
{
    const int i = threadIdx.x;
    if (i >= 2 * 97) return;
    const int s = i / 97, j = i % 97;
    const float invHW = 1.f / (float)HW;
    float val;
    if (j == 0) {
        float acc = 0.f;
        for (int g = 0; g < NGATH; ++g) acc += ws[(size_t)(GATH_BASE + g) * 8 + s];
        val = acc / (float)(KP1 * BB);
    } else if (j < 33) {
        const int b = j - 1;
        float acc = 0.f;
        if (s == 0) {
            for (int k = 0; k < 32; ++k)
                acc += ws[(size_t)(S0_BASE + b * 32 + k) * 8 + 0];
        } else {
            for (int k = 0; k < 32; ++k)
                acc += ws[(size_t)(S1_BASE + b * 32 + k) * 8 + 0]
                     + ws[(size_t)(S0_BASE + b * 32 + k) * 8 + 3];
        }
        val = acc * invHW;
    } else if (j < 65) {
        const int b = j - 33;
        float acc = 0.f;
        if (s == 0) {
            for (int k = 0; k < 32; ++k)
                acc += ws[(size_t)(S0_BASE + b * 32 + k) * 8 + 1];
        } else {
            for (int k = 0; k < 32; ++k)
                acc += ws[(size_t)(S1_BASE + b * 32 + k) * 8 + 1]
                     + ws[(size_t)(S0_BASE + b * 32 + k) * 8 + 4];
        }
        val = 0.25f * acc * invHW;
    } else {
        const int b = j - 65;
        float sp = 0.f, num = 0.f;
        for (int k = 0; k < 32; ++k) {
            const float* sl = ws + (size_t)(S0_BASE + b * 32 + k) * 8;
            sp  += sl[2];
            num += sl[5 + s];
        }
        val = (sp > 0.f) ? (num / sp) : (num * invHW);
    }
    out[i] = val;
}

extern "C" void kernel_launch(void* const* d_in, const int* in_sizes, int n_in,
                              void* d_out, int out_size, void* d_ws, size_t ws_size,
                              hipStream_t stream) {
    const float* out0      = (const float*)d_in[0];
    const float* out1      = (const float*)d_in[1];
    const float* t_corner  = (const float*)d_in[2];
    const float* t_co      = (const float*)d_in[3];
    const float* t_bin     = (const float*)d_in[4];
    const int*   anchors   = (const int*)d_in[5];
    const int*   positives = (const int*)d_in[6];
    const int*   neg_zero  = (const int*)d_in[7];
    const int*   neg_other = (const int*)d_in[8];
    float* ws  = (float*)d_ws;
    float* out = (float*)d_out;

    ml_partial_kernel<<<GRID, 256, 0, stream>>>(out0, out1, t_corner, t_co, t_bin,
                                                anchors, positives, neg_zero,
                                                neg_other, ws);
    ml_finish_kernel<<<1, 256, 0, stream>>>(ws, out);
}